// Round 10
// baseline (96.063 us; speedup 1.0000x reference)
//
#include <hip/hip_runtime.h>

#define NBATCH 16
#define CIN_ 128
#define COUT_ 128
#define H_ 128
#define W_ 128
#define TH 4               // output rows per workgroup
#define NR (TH + 2)        // staged input rows
#define CPITCH 34          // ci pitch in LDS tile (r4-proven layout)

typedef short bf16x8 __attribute__((ext_vector_type(8)));
typedef float f32x4 __attribute__((ext_vector_type(4)));

__device__ __forceinline__ unsigned short f32_to_bf16(float f) {
  unsigned int u = __float_as_uint(f);
  u += 0x7fffu + ((u >> 16) & 1u);   // round-to-nearest-even
  return (unsigned short)(u >> 16);
}

// mask-block bits for output block ob: bit ib set if (ob,ib) kept.
// All waves compute identical result via ballot over lanes 0..3. [r8/r9-verified]
__device__ __forceinline__ int mask_bits(const float* __restrict__ mask, int ob, int lane) {
  float mv = (lane < 4) ? mask[((size_t)(ob * 32) * CIN_ + lane * 32) * 9] : 0.0f;
  unsigned long long bal = __ballot(mv != 0.0f);
  return (int)(bal & 15ull);
}

// ---------------- kernel 1: pack masked weights to bf16, MFMA A-layout -------
// wpack[ob][slot][khkw][co(32)][ci(32)]  (ci contiguous)
__global__ __launch_bounds__(256) void pack_w_k(const float* __restrict__ weight,
                                                const float* __restrict__ mask,
                                                unsigned short* __restrict__ wpack) {
  const int khkw = blockIdx.x;   // 0..8
  const int slot = blockIdx.y;   // 0..3
  const int ob   = blockIdx.z;   // 0..3
  const int mb = mask_bits(mask, ob, threadIdx.x & 63);
  if (slot >= __popc(mb)) return;
  int m = mb;
  for (int t = 0; t < slot; ++t) m &= m - 1;
  const int ib = __ffs(m) - 1;
  const int kh = khkw / 3, kw = khkw % 3;
  for (int e = threadIdx.x; e < 1024; e += 256) {
    const int co = e >> 5, ci = e & 31;
    const int cog = ob * 32 + co, cig = ib * 32 + ci;
    const size_t widx = ((size_t)(cog * CIN_ + cig) * 3 + kh) * 3 + kw;
    const float v = weight[widx] * mask[widx];
    wpack[(size_t)((ob * 4 + slot) * 9 + khkw) * 1024 + e] = f32_to_bf16(v);
  }
}

// ---------------- kernel 2: fused transpose+conv (block-sparse implicit GEMM)
// grid: (H/TH, B, 4 output blocks), block 256 (4 waves over w).
// r4 body; staging loads batch-issued 24-deep into registers (MLP), 2 WG/CU.
__global__ __launch_bounds__(256, 2) void conv_fused_k(const float* __restrict__ x,
                                                       const unsigned short* __restrict__ wpack,
                                                       const float* __restrict__ mask,
                                                       const float* __restrict__ bias,
                                                       float* __restrict__ out) {
  __shared__ unsigned short xs[NR * 130 * CPITCH];   // 53 KB

  const int tid  = threadIdx.x;
  const int wave = tid >> 6;
  const int lane = tid & 63;
  const int wl   = lane & 15;     // MFMA row/col index
  const int kg   = lane >> 4;     // k-group (8 consecutive k per lane)

  const int h0 = blockIdx.x * TH;
  const int b  = blockIdx.y;
  const int ob = blockIdx.z;
  const int w0 = wave * 32;

  const int mb  = mask_bits(mask, ob, lane);
  const int cnt = __popc(mb);

  f32x4 acc[TH][2][2] = {};

  // staging decomposition: quad q = w/4, group g picks (row, ci-pair)
  const int q = tid & 31;         // w quad: w = q*4 + j
  const int g = tid >> 5;         // 0..7

  int mrem = mb;
  for (int s = 0; s < cnt; ++s) {
    const int ib = __ffs(mrem) - 1;
    mrem &= mrem - 1;

    if (s) __syncthreads();   // previous compute done reading xs

    // ---- stage x[b][ib*32..+31][h0-1..h0+TH][*] -> xs (bf16, transposed) ----
    // Phase 1: issue ALL 24 dwordx4 loads into registers (deep MLP).
    const float* xbase = x + ((size_t)b * CIN_ + ib * 32) * H_ * W_ + q * 4;
    f32x4 Ra[12], Rb[12];
#pragma unroll
    for (int it = 0; it < 12; ++it) {
      const int combo = it * 8 + g;       // 0..95
      const int r  = combo >> 4;          // 0..5
      const int cp = combo & 15;          // ci pair index
      const int row = h0 - 1 + r;
      const bool rv = (row >= 0) && (row < H_);
      const float* src = xbase + ((size_t)(cp * 2) * H_ + (rv ? row : 0)) * W_;
      Ra[it] = *(const f32x4*)src;
      Rb[it] = *(const f32x4*)(src + (size_t)H_ * W_);
    }

    // A-fragment loads: independent global loads, join the in-flight queue.
    const unsigned short* wk =
        wpack + (size_t)((ob * 4 + s) * 9) * 1024 + wl * 32 + kg * 8;
    bf16x8 a[3][3][2];
#pragma unroll
    for (int kh = 0; kh < 3; ++kh)
#pragma unroll
      for (int kw = 0; kw < 3; ++kw) {
        a[kh][kw][0] = *(const bf16x8*)(wk + (kh * 3 + kw) * 1024);
        a[kh][kw][1] = *(const bf16x8*)(wk + (kh * 3 + kw) * 1024 + 16 * 32);
      }

    // Phase 2: cvt + LDS writes (r4 layout, verbatim).
#pragma unroll
    for (int it = 0; it < 12; ++it) {
      const int combo = it * 8 + g;
      const int r  = combo >> 4;
      const int cp = combo & 15;
      const int row = h0 - 1 + r;
      const bool rv = (row >= 0) && (row < H_);
      unsigned int* xd = (unsigned int*)(xs + (r * 130 + q * 4 + 1) * CPITCH + cp * 2);
#pragma unroll
      for (int j = 0; j < 4; ++j) {
        unsigned int lo = rv ? (unsigned int)f32_to_bf16(Ra[it][j]) : 0u;
        unsigned int hi = rv ? (unsigned int)f32_to_bf16(Rb[it][j]) : 0u;
        xd[j * (CPITCH / 2)] = lo | (hi << 16);
      }
    }
    // zero the w' = 0 and w' = 129 padding columns (NR*2*32 = 384 elems)
    for (int e = tid; e < NR * 2 * 32; e += 256) {
      const int r = e >> 6, edge = (e >> 5) & 1, cc = e & 31;
      xs[(r * 130 + (edge ? 129 : 0)) * CPITCH + cc] = 0;
    }

    __syncthreads();   // tile staged

    // ---- compute: input-row-major, B frags from LDS (r4 verbatim) ----
#pragma unroll
    for (int ridx = 0; ridx < NR; ++ridx) {
      bf16x8 bf[2][3];
#pragma unroll
      for (int ni = 0; ni < 2; ++ni)
#pragma unroll
        for (int kw = 0; kw < 3; ++kw)
          bf[ni][kw] = *(const bf16x8*)(xs + (ridx * 130 + w0 + ni * 16 + wl + kw) * CPITCH + kg * 8);

#pragma unroll
      for (int kh = 0; kh < 3; ++kh) {
        const int hi = ridx - kh;           // output row h0+hi uses input r with tap kh
        if (hi < 0 || hi >= TH) continue;   // compile-time prune
#pragma unroll
        for (int kw = 0; kw < 3; ++kw) {
          acc[hi][0][0] = __builtin_amdgcn_mfma_f32_16x16x32_bf16(a[kh][kw][0], bf[0][kw], acc[hi][0][0], 0, 0, 0);
          acc[hi][0][1] = __builtin_amdgcn_mfma_f32_16x16x32_bf16(a[kh][kw][0], bf[1][kw], acc[hi][0][1], 0, 0, 0);
          acc[hi][1][0] = __builtin_amdgcn_mfma_f32_16x16x32_bf16(a[kh][kw][1], bf[0][kw], acc[hi][1][0], 0, 0, 0);
          acc[hi][1][1] = __builtin_amdgcn_mfma_f32_16x16x32_bf16(a[kh][kw][1], bf[1][kw], acc[hi][1][1], 0, 0, 0);
        }
      }
    }
  }

  // ---- epilogue: plain scalar stores (r4 verbatim) ----
  // acc layout [HW-verified r1]: co = mi*16 + kg*4 + j, w = w0 + ni*16 + wl.
#pragma unroll
  for (int mi = 0; mi < 2; ++mi)
#pragma unroll
    for (int j = 0; j < 4; ++j) {
      const int co = mi * 16 + kg * 4 + j;
      const float bv = bias[ob * 32 + co];
#pragma unroll
      for (int hh = 0; hh < TH; ++hh) {
        float* yrow = out + ((size_t)(b * COUT_ + ob * 32 + co) * H_ + h0 + hh) * W_;
        yrow[w0 + wl]      = acc[hh][mi][0][j] + bv;
        yrow[w0 + wl + 16] = acc[hh][mi][1][j] + bv;
      }
    }
}

extern "C" void kernel_launch(void* const* d_in, const int* in_sizes, int n_in,
                              void* d_out, int out_size, void* d_ws, size_t ws_size,
                              hipStream_t stream) {
  const float* x      = (const float*)d_in[0];
  const float* weight = (const float*)d_in[1];
  const float* bias   = (const float*)d_in[2];
  const float* mask   = (const float*)d_in[3];
  float* out = (float*)d_out;

  unsigned short* wpack = (unsigned short*)d_ws;   // 288 KB

  pack_w_k<<<dim3(9, 4, 4), 256, 0, stream>>>(weight, mask, wpack);
  conv_fused_k<<<dim3(H_ / TH, NBATCH, 4), 256, 0, stream>>>(x, wpack, mask, bias, out);
}

// Round 11
// 82.173 us; speedup vs baseline: 1.1690x; 1.1690x over previous
//
#include <hip/hip_runtime.h>

#define NBATCH 16
#define CIN_ 128
#define COUT_ 128
#define H_ 128
#define W_ 128
#define TH 4               // output rows per workgroup
#define NR (TH + 2)        // staged input rows
#define CPITCH 34          // ci pitch in LDS tile (r4-proven layout)

typedef short bf16x8 __attribute__((ext_vector_type(8)));
typedef float f32x4 __attribute__((ext_vector_type(4)));

__device__ __forceinline__ unsigned short f32_to_bf16(float f) {
  unsigned int u = __float_as_uint(f);
  u += 0x7fffu + ((u >> 16) & 1u);   // round-to-nearest-even
  return (unsigned short)(u >> 16);
}

// mask-block bits for output block ob: bit ib set if (ob,ib) kept.
// All waves compute identical result via ballot over lanes 0..3. [r8-r10 verified]
__device__ __forceinline__ int mask_bits(const float* __restrict__ mask, int ob, int lane) {
  float mv = (lane < 4) ? mask[((size_t)(ob * 32) * CIN_ + lane * 32) * 9] : 0.0f;
  unsigned long long bal = __ballot(mv != 0.0f);
  return (int)(bal & 15ull);
}

// ---------------- kernel 1: pack masked weights to bf16, MFMA A-layout -------
// wpack[ob][slot][khkw][co(32)][ci(32)]  (ci contiguous, ascending-ib slots)
__global__ __launch_bounds__(256) void pack_w_k(const float* __restrict__ weight,
                                                const float* __restrict__ mask,
                                                unsigned short* __restrict__ wpack) {
  const int khkw = blockIdx.x;   // 0..8
  const int slot = blockIdx.y;   // 0..3
  const int ob   = blockIdx.z;   // 0..3
  const int mb = mask_bits(mask, ob, threadIdx.x & 63);
  if (slot >= __popc(mb)) return;
  int m = mb;
  for (int t = 0; t < slot; ++t) m &= m - 1;
  const int ib = __ffs(m) - 1;
  const int kh = khkw / 3, kw = khkw % 3;
  for (int e = threadIdx.x; e < 1024; e += 256) {
    const int co = e >> 5, ci = e & 31;
    const int cog = ob * 32 + co, cig = ib * 32 + ci;
    const size_t widx = ((size_t)(cog * CIN_ + cig) * 3 + kh) * 3 + kw;
    const float v = weight[widx] * mask[widx];
    wpack[(size_t)((ob * 4 + slot) * 9 + khkw) * 1024 + e] = f32_to_bf16(v);
  }
}

// ---------------- kernel 2: fused transpose+conv (block-sparse implicit GEMM)
// grid: (H/TH, B, 4 output blocks), block 256 (4 waves over w), 3 WG/CU.
// r4 body verbatim; only the ib-list comes from ballot instead of make_lists.
__global__ __launch_bounds__(256, 3) void conv_fused_k(const float* __restrict__ x,
                                                       const unsigned short* __restrict__ wpack,
                                                       const float* __restrict__ mask,
                                                       const float* __restrict__ bias,
                                                       float* __restrict__ out) {
  __shared__ unsigned short xs[NR * 130 * CPITCH];   // 53 KB

  const int tid  = threadIdx.x;
  const int wave = tid >> 6;
  const int lane = tid & 63;
  const int wl   = lane & 15;     // MFMA row/col index
  const int kg   = lane >> 4;     // k-group (8 consecutive k per lane)

  const int h0 = blockIdx.x * TH;
  const int b  = blockIdx.y;
  const int ob = blockIdx.z;
  const int w0 = wave * 32;

  const int mb  = mask_bits(mask, ob, lane);
  const int cnt = __popc(mb);

  f32x4 acc[TH][2][2] = {};

  // staging decomposition: quad q = w/4, group g picks (row, ci-pair)
  const int q = tid & 31;         // w quad: w = q*4 + j
  const int g = tid >> 5;         // 0..7

  int mrem = mb;
  for (int s = 0; s < cnt; ++s) {
    const int ib = __ffs(mrem) - 1;
    mrem &= mrem - 1;

    if (s) __syncthreads();   // previous compute done reading xs

    // ---- stage x[b][ib*32..+31][h0-1..h0+TH][*] -> xs (bf16, transposed) ----
    {
      const float* xbase = x + ((size_t)b * CIN_ + ib * 32) * H_ * W_ + q * 4;
#pragma unroll
      for (int it = 0; it < 12; ++it) {
        const int combo = it * 8 + g;       // 0..95
        const int r  = combo >> 4;          // 0..5
        const int cp = combo & 15;          // ci pair index
        const int row = h0 - 1 + r;
        const bool rv = (row >= 0) && (row < H_);
        const float* src = xbase + ((size_t)(cp * 2) * H_ + (rv ? row : 0)) * W_;
        f32x4 va = *(const f32x4*)src;
        f32x4 vb = *(const f32x4*)(src + (size_t)H_ * W_);
        unsigned int* xd = (unsigned int*)(xs + (r * 130 + q * 4 + 1) * CPITCH + cp * 2);
#pragma unroll
        for (int j = 0; j < 4; ++j) {
          unsigned int lo = rv ? (unsigned int)f32_to_bf16(va[j]) : 0u;
          unsigned int hi = rv ? (unsigned int)f32_to_bf16(vb[j]) : 0u;
          xd[j * (CPITCH / 2)] = lo | (hi << 16);
        }
      }
      // zero the w' = 0 and w' = 129 padding columns (NR*2*32 = 384 elems)
      for (int e = tid; e < NR * 2 * 32; e += 256) {
        const int r = e >> 6, edge = (e >> 5) & 1, cc = e & 31;
        xs[(r * 130 + (edge ? 129 : 0)) * CPITCH + cc] = 0;
      }
    }

    // ---- hoist all 18 A fragments (L2-hot; latency hides under barrier) ----
    const unsigned short* wk =
        wpack + (size_t)((ob * 4 + s) * 9) * 1024 + wl * 32 + kg * 8;
    bf16x8 a[3][3][2];
#pragma unroll
    for (int kh = 0; kh < 3; ++kh)
#pragma unroll
      for (int kw = 0; kw < 3; ++kw) {
        a[kh][kw][0] = *(const bf16x8*)(wk + (kh * 3 + kw) * 1024);
        a[kh][kw][1] = *(const bf16x8*)(wk + (kh * 3 + kw) * 1024 + 16 * 32);
      }

    __syncthreads();   // tile staged

    // ---- compute: input-row-major, B frags from LDS (r4 verbatim) ----
#pragma unroll
    for (int ridx = 0; ridx < NR; ++ridx) {
      bf16x8 bf[2][3];
#pragma unroll
      for (int ni = 0; ni < 2; ++ni)
#pragma unroll
        for (int kw = 0; kw < 3; ++kw)
          bf[ni][kw] = *(const bf16x8*)(xs + (ridx * 130 + w0 + ni * 16 + wl + kw) * CPITCH + kg * 8);

#pragma unroll
      for (int kh = 0; kh < 3; ++kh) {
        const int hi = ridx - kh;           // output row h0+hi uses input r with tap kh
        if (hi < 0 || hi >= TH) continue;   // compile-time prune
#pragma unroll
        for (int kw = 0; kw < 3; ++kw) {
          acc[hi][0][0] = __builtin_amdgcn_mfma_f32_16x16x32_bf16(a[kh][kw][0], bf[0][kw], acc[hi][0][0], 0, 0, 0);
          acc[hi][0][1] = __builtin_amdgcn_mfma_f32_16x16x32_bf16(a[kh][kw][0], bf[1][kw], acc[hi][0][1], 0, 0, 0);
          acc[hi][1][0] = __builtin_amdgcn_mfma_f32_16x16x32_bf16(a[kh][kw][1], bf[0][kw], acc[hi][1][0], 0, 0, 0);
          acc[hi][1][1] = __builtin_amdgcn_mfma_f32_16x16x32_bf16(a[kh][kw][1], bf[1][kw], acc[hi][1][1], 0, 0, 0);
        }
      }
    }
  }

  // ---- epilogue: plain scalar stores (r4 verbatim) ----
  // acc layout [HW-verified r1]: co = mi*16 + kg*4 + j, w = w0 + ni*16 + wl.
#pragma unroll
  for (int mi = 0; mi < 2; ++mi)
#pragma unroll
    for (int j = 0; j < 4; ++j) {
      const int co = mi * 16 + kg * 4 + j;
      const float bv = bias[ob * 32 + co];
#pragma unroll
      for (int hh = 0; hh < TH; ++hh) {
        float* yrow = out + ((size_t)(b * COUT_ + ob * 32 + co) * H_ + h0 + hh) * W_;
        yrow[w0 + wl]      = acc[hh][mi][0][j] + bv;
        yrow[w0 + wl + 16] = acc[hh][mi][1][j] + bv;
      }
    }
}

extern "C" void kernel_launch(void* const* d_in, const int* in_sizes, int n_in,
                              void* d_out, int out_size, void* d_ws, size_t ws_size,
                              hipStream_t stream) {
  const float* x      = (const float*)d_in[0];
  const float* weight = (const float*)d_in[1];
  const float* bias   = (const float*)d_in[2];
  const float* mask   = (const float*)d_in[3];
  float* out = (float*)d_out;

  unsigned short* wpack = (unsigned short*)d_ws;   // 288 KB

  pack_w_k<<<dim3(9, 4, 4), 256, 0, stream>>>(weight, mask, wpack);
  conv_fused_k<<<dim3(H_ / TH, NBATCH, 4), 256, 0, stream>>>(x, wpack, mask, bias, out);
}